// Round 1
// baseline (15137.396 us; speedup 1.0000x reference)
//
#include <hip/hip_runtime.h>
#include <math.h>

// ---------------- problem constants ----------------
#define B_    128
#define T_    64
#define INX   512
#define CTRL  512
#define NN    128   // memory slots
#define MMM   128   // memory width
#define RR    4     // read heads
#define LL    134   // 3 + MM + S
#define NOUT  926   // R*L + W*LW
#define NOUTP 928   // padded stride
#define NWG   256
#define NTHR  256

// Mem row stride 130: bank(130n+m)%32 = (2n+m)%32 -> 2-way (free) on n-varying access
#define MSTR  130

struct __align__(16) SM {
  float Mem[NN][MSTR];       // 66,560 B  (persistent, WGs < 128)
  float rw[RR][NN];          //  2,048 B  (persistent)
  float ww[NN];              //    512 B  (persistent)
  float instr[NOUTP];        //  3,712 B  (phase D)
  union {
    struct { float At[16][68]; float Bt[32][68]; } mm;   // k-major tiles, 13,056 B
    struct { float red[256]; float wi[128]; float invn[128]; float scal[16]; } d;
  } u;
};  // ~85.9 KB -> exactly 1 WG/CU (co-residency for grid barrier)

// ---------------- grid barrier (two-level, agent scope) ----------------
__device__ __forceinline__ void grid_sync(int* bar) {
  __syncthreads();
  if (threadIdx.x == 0) {
    __threadfence();                       // release: writeback XCD L2
    int* gcnt = bar + (blockIdx.x & 7) * 16;
    int* root = bar + 8 * 16;
    int* gen  = bar + 8 * 16 + 16;
    int g = __hip_atomic_load(gen, __ATOMIC_RELAXED, __HIP_MEMORY_SCOPE_AGENT);
    int a = __hip_atomic_fetch_add(gcnt, 1, __ATOMIC_ACQ_REL, __HIP_MEMORY_SCOPE_AGENT);
    if (a == 31) {                         // last of my 32-WG group
      __hip_atomic_store(gcnt, 0, __ATOMIC_RELAXED, __HIP_MEMORY_SCOPE_AGENT);
      int r = __hip_atomic_fetch_add(root, 1, __ATOMIC_ACQ_REL, __HIP_MEMORY_SCOPE_AGENT);
      if (r == 7) {                        // last group
        __hip_atomic_store(root, 0, __ATOMIC_RELAXED, __HIP_MEMORY_SCOPE_AGENT);
        __hip_atomic_fetch_add(gen, 1, __ATOMIC_ACQ_REL, __HIP_MEMORY_SCOPE_AGENT);
      }
    }
    int it = 0;
    while (__hip_atomic_load(gen, __ATOMIC_ACQUIRE, __HIP_MEMORY_SCOPE_AGENT) == g) {
      __builtin_amdgcn_s_sleep(2);
      if (++it > (1 << 22)) break;         // safety: wrong-answer beats hang
    }
    __threadfence();                       // acquire: invalidate stale L2
  }
  __syncthreads();
}

// ---------------- block reductions over 256 threads ----------------
__device__ __forceinline__ float red_sum256(float v, volatile float* scal) {
  #pragma unroll
  for (int m = 32; m >= 1; m >>= 1) v += __shfl_xor(v, m);
  int tid = threadIdx.x;
  if ((tid & 63) == 0) scal[tid >> 6] = v;
  __syncthreads();
  float r = scal[0] + scal[1] + scal[2] + scal[3];
  __syncthreads();
  return r;
}
__device__ __forceinline__ float red_max256(float v, volatile float* scal) {
  #pragma unroll
  for (int m = 32; m >= 1; m >>= 1) v = fmaxf(v, __shfl_xor(v, m));
  int tid = threadIdx.x;
  if ((tid & 63) == 0) scal[tid >> 6] = v;
  __syncthreads();
  float r = fmaxf(fmaxf(scal[0], scal[1]), fmaxf(scal[2], scal[3]));
  __syncthreads();
  return r;
}

// ---------------- precompute: d_out = X(8192x512) @ Wc[0:512,:] + bc ----------------
__global__ __launch_bounds__(256) void pre_mm(const float* __restrict__ X,
                                              const float* __restrict__ Wc,
                                              const float* __restrict__ bc,
                                              float* __restrict__ out) {
  __shared__ float Xs[16][68];   // [k][row]
  __shared__ float Ws[16][64];   // [k][col]
  const int wg = blockIdx.x;          // 128 row-tiles x 8 col-tiles
  const int r0 = (wg >> 3) * 64, c0 = (wg & 7) * 64;
  const int tid = threadIdx.x;
  const int ti = tid >> 4, tj = tid & 15;   // 4x4 outputs per thread
  float acc[4][4] = {};
  for (int kk = 0; kk < 512; kk += 16) {
    __syncthreads();
    for (int e = tid; e < 1024; e += 256) {
      int i = e >> 4, k = e & 15;
      Xs[k][i] = X[(size_t)(r0 + i) * 512 + kk + k];
    }
    for (int e = tid; e < 1024; e += 256) {
      int k = e >> 6, j = e & 63;
      Ws[k][j] = Wc[(size_t)(kk + k) * CTRL + c0 + j];
    }
    __syncthreads();
    #pragma unroll
    for (int k = 0; k < 16; ++k) {
      float a0 = Xs[k][ti*4+0], a1 = Xs[k][ti*4+1], a2 = Xs[k][ti*4+2], a3 = Xs[k][ti*4+3];
      float b0 = Ws[k][tj*4+0], b1 = Ws[k][tj*4+1], b2 = Ws[k][tj*4+2], b3 = Ws[k][tj*4+3];
      acc[0][0]+=a0*b0; acc[0][1]+=a0*b1; acc[0][2]+=a0*b2; acc[0][3]+=a0*b3;
      acc[1][0]+=a1*b0; acc[1][1]+=a1*b1; acc[1][2]+=a1*b2; acc[1][3]+=a1*b3;
      acc[2][0]+=a2*b0; acc[2][1]+=a2*b1; acc[2][2]+=a2*b2; acc[2][3]+=a2*b3;
      acc[3][0]+=a3*b0; acc[3][1]+=a3*b1; acc[3][2]+=a3*b2; acc[3][3]+=a3*b3;
    }
  }
  #pragma unroll
  for (int i = 0; i < 4; ++i) {
    size_t o = (size_t)(r0 + ti*4 + i) * 512 + c0 + tj*4;
    float4 v = { acc[i][0] + bc[c0+tj*4+0], acc[i][1] + bc[c0+tj*4+1],
                 acc[i][2] + bc[c0+tj*4+2], acc[i][3] + bc[c0+tj*4+3] };
    *(float4*)&out[o] = v;
  }
}

// ---------------- persistent recurrence kernel ----------------
__global__ __launch_bounds__(256) void ntm_main(const float* __restrict__ Wc,
                                                const float* __restrict__ Wk,
                                                const float* __restrict__ bk,
                                                float* __restrict__ out,
                                                float* __restrict__ instrs,
                                                float* __restrict__ rv,
                                                int* bar) {
  __shared__ SM sm;
  const int wg = blockIdx.x, tid = threadIdx.x;

  // ---- init state ----
  if (wg < B_) {
    for (int e = tid; e < NN * MMM; e += NTHR) {
      int n = e >> 7, m = e & 127;
      sm.Mem[n][m] = (n == NN / 2) ? 1.0f : 0.0f;
    }
    for (int e = tid; e < RR * NN; e += NTHR) sm.rw[e >> 7][e & 127] = 0.0f;
    if (tid < NN) sm.ww[tid] = 0.0f;
  }
  { int e = wg * NTHR + tid; rv[e] = 0.0f; }   // 65536 = exactly one elem/thread
  grid_sync(bar);

  for (int t = 0; t < T_; ++t) {
    // ===== phase B: out[b][t][:] = tanh(P + rv @ Wc[512:,:]) =====
    // 128 WGs, tile 16 rows x 32 cols, thread -> cols (j2, j2+16)
    if (wg < 128) {
      const int b0 = (wg >> 4) * 16, c0 = (wg & 15) * 32;
      const int i = tid >> 4, j2 = tid & 15;
      float acc0 = 0.f, acc1 = 0.f;
      for (int kk = 0; kk < RR * MMM; kk += 64) {
        __syncthreads();
        for (int e = tid; e < 1024; e += NTHR) {     // At[row][k]
          int il = e >> 6, kl = e & 63;
          sm.u.mm.At[il][kl] = rv[(size_t)(b0 + il) * 512 + kk + kl];
        }
        for (int e = tid; e < 2048; e += NTHR) {     // Bt[col][k]
          int kl = e >> 5, jl = e & 31;
          sm.u.mm.Bt[jl][kl] = Wc[(size_t)(INX + kk + kl) * CTRL + c0 + jl];
        }
        __syncthreads();
        #pragma unroll
        for (int k4 = 0; k4 < 64; k4 += 4) {
          float4 a  = *(const float4*)&sm.u.mm.At[i][k4];
          float4 w0 = *(const float4*)&sm.u.mm.Bt[j2][k4];
          float4 w1 = *(const float4*)&sm.u.mm.Bt[j2 + 16][k4];
          acc0 += a.x*w0.x + a.y*w0.y + a.z*w0.z + a.w*w0.w;
          acc1 += a.x*w1.x + a.y*w1.y + a.z*w1.z + a.w*w1.w;
        }
      }
      size_t o0 = ((size_t)(b0 + i) * T_ + t) * CTRL + c0 + j2;
      out[o0]      = tanhf(out[o0]      + acc0);
      out[o0 + 16] = tanhf(out[o0 + 16] + acc1);
    }
    grid_sync(bar);

    // ===== phase C: instrs = out_t @ Wk + bk =====
    // 232 WGs, tile 16 rows x 32 cols over 928 padded cols
    if (wg < 232) {
      const int b0 = (wg / 29) * 16, c0 = (wg % 29) * 32;
      const int i = tid >> 4, j2 = tid & 15;
      float acc0 = 0.f, acc1 = 0.f;
      for (int kk = 0; kk < CTRL; kk += 64) {
        __syncthreads();
        for (int e = tid; e < 1024; e += NTHR) {
          int il = e >> 6, kl = e & 63;
          sm.u.mm.At[il][kl] = out[((size_t)(b0 + il) * T_ + t) * CTRL + kk + kl];
        }
        for (int e = tid; e < 2048; e += NTHR) {
          int kl = e >> 5, jl = e & 31;
          int c = c0 + jl;
          sm.u.mm.Bt[jl][kl] = (c < NOUT) ? Wk[(size_t)(kk + kl) * NOUT + c] : 0.f;
        }
        __syncthreads();
        #pragma unroll
        for (int k4 = 0; k4 < 64; k4 += 4) {
          float4 a  = *(const float4*)&sm.u.mm.At[i][k4];
          float4 w0 = *(const float4*)&sm.u.mm.Bt[j2][k4];
          float4 w1 = *(const float4*)&sm.u.mm.Bt[j2 + 16][k4];
          acc0 += a.x*w0.x + a.y*w0.y + a.z*w0.z + a.w*w0.w;
          acc1 += a.x*w1.x + a.y*w1.y + a.z*w1.z + a.w*w1.w;
        }
      }
      int c = c0 + j2;
      float bias0 = (c      < NOUT) ? bk[c]      : 0.f;
      float bias1 = (c + 16 < NOUT) ? bk[c + 16] : 0.f;
      instrs[(size_t)(b0 + i) * NOUTP + c]      = acc0 + bias0;
      instrs[(size_t)(b0 + i) * NOUTP + c + 16] = acc1 + bias1;
    }
    grid_sync(bar);

    // ===== phase D: per-batch heads + Mem update + rv =====
    if (wg < B_) {
      const int b = wg;
      for (int e = tid; e < NOUT; e += NTHR) sm.instr[e] = instrs[(size_t)b * NOUTP + e];
      __syncthreads();
      // column inv-norms over n (reference: _l2n(Mem, axis=1))
      {
        int m = tid & 127, h = tid >> 7;
        float p = 0.f;
        #pragma unroll 8
        for (int q = 0; q < 64; ++q) { float v = sm.Mem[h * 64 + q][m]; p += v * v; }
        sm.u.d.red[tid] = p;
      }
      __syncthreads();
      if (tid < 128) sm.u.d.invn[tid] = rsqrtf(fmaxf(sm.u.d.red[tid] + sm.u.d.red[tid + 128], 1e-12f));
      __syncthreads();

      for (int hd = 0; hd < 5; ++hd) {
        const int off = (hd < RR) ? hd * LL : RR * LL;
        // key norm
        float kv = (tid < 128) ? sm.instr[off + tid] : 0.f;
        float kn2 = red_sum256(kv * kv, sm.u.d.scal);
        float invk = rsqrtf(fmaxf(kn2, 1e-12f));
        // scalar head params (computed redundantly by every thread)
        float bb = expf(sm.instr[off + 128]);
        float gg = 1.f / (1.f + expf(-sm.instr[off + 129]));
        float s0 = sm.instr[off + 130], s1 = sm.instr[off + 131], s2 = sm.instr[off + 132];
        float smx = fmaxf(s0, fmaxf(s1, s2));
        float e0 = expf(s0 - smx), e1 = expf(s1 - smx), e2 = expf(s2 - smx);
        float esm = e0 + e1 + e2; s0 = e0 / esm; s1 = e1 / esm; s2 = e2 / esm;
        float spx = sm.instr[off + 133];
        float tt = ((spx > 20.f) ? spx : log1pf(expf(spx))) + 1.0f;
        // sim[n] = (sum_m Mem[n][m]*invn[m]*k[m]) * invk   (m index skewed by n for banks)
        {
          int n = tid & 127, h = tid >> 7;
          float p = 0.f;
          #pragma unroll 8
          for (int q = 0; q < 64; ++q) {
            int m = h * 64 + ((q + n) & 63);
            p += sm.Mem[n][m] * sm.u.d.invn[m] * sm.instr[off + m];
          }
          sm.u.d.red[tid] = p;
        }
        __syncthreads();
        float simv = -1e30f, evv = 0.f;
        if (tid < 128) simv = (sm.u.d.red[tid] + sm.u.d.red[tid + 128]) * invk * bb;
        float mx = red_max256(simv, sm.u.d.scal);
        if (tid < 128) evv = expf(simv - mx);
        float es = red_sum256(evv, sm.u.d.scal);
        if (tid < 128) {
          float wcv = evv / es;
          float wold = (hd < RR) ? sm.rw[hd][tid] : sm.ww[tid];
          sm.u.d.wi[tid] = gg * wcv + (1.f - gg) * wold;
        }
        __syncthreads();
        float pv = 0.f;
        if (tid < 128) {
          float wsv = s0 * sm.u.d.wi[(tid + 127) & 127] + s1 * sm.u.d.wi[tid]
                    + s2 * sm.u.d.wi[(tid + 1) & 127];
          pv = powf(wsv, tt);
        }
        float ps = red_sum256(pv, sm.u.d.scal);
        if (tid < 128) {
          float wn = pv / (ps + 1e-12f);
          if (hd < RR) sm.rw[hd][tid] = wn; else sm.ww[tid] = wn;
        }
        __syncthreads();
      }
      // Mem = Mem*(1 - ww[n]*e[m]) + ww[n]*a[m]
      for (int e = tid; e < NN * MMM; e += NTHR) {
        int n = e >> 7, m = e & 127;
        float w = sm.ww[n];
        sm.Mem[n][m] = sm.Mem[n][m] * (1.f - w * sm.instr[670 + m]) + w * sm.instr[798 + m];
      }
      __syncthreads();
      // rv[r][m] = sum_n Mem[n][m] * rw[r][n]
      for (int e = tid; e < RR * MMM; e += NTHR) {
        int r = e >> 7, m = e & 127;
        float acc = 0.f;
        #pragma unroll 8
        for (int n = 0; n < NN; ++n) acc += sm.Mem[n][m] * sm.rw[r][n];
        rv[(size_t)b * (RR * MMM) + e] = acc;
      }
    }
    grid_sync(bar);
  }
}

// ---------------- launch ----------------
extern "C" void kernel_launch(void* const* d_in, const int* in_sizes, int n_in,
                              void* d_out, int out_size, void* d_ws, size_t ws_size,
                              hipStream_t stream) {
  const float* x  = (const float*)d_in[0];
  const float* Wc = (const float*)d_in[1];
  const float* bc = (const float*)d_in[2];
  const float* Wk = (const float*)d_in[3];
  const float* bk = (const float*)d_in[4];
  float* out = (float*)d_out;

  char* ws = (char*)d_ws;
  int*   bar    = (int*)ws;                                   // 1 KB
  float* instrs = (float*)(ws + 1024);                        // 128*928 f32
  float* rv     = (float*)(ws + 1024 + B_ * NOUTP * 4);       // 128*512 f32

  hipMemsetAsync(bar, 0, 1024, stream);
  pre_mm<<<dim3(1024), dim3(256), 0, stream>>>(x, Wc, bc, out);
  ntm_main<<<dim3(NWG), dim3(NTHR), 0, stream>>>(Wc, Wk, bk, out, instrs, rv, bar);
}

// Round 2
// 3922.038 us; speedup vs baseline: 3.8596x; 3.8596x over previous
//
#include <hip/hip_runtime.h>
#include <math.h>

// ---------------- problem constants ----------------
#define B_    128
#define T_    64
#define INX   512
#define CTRL  512
#define NN    128
#define MMM   128
#define RR    4
#define LLh   134   // per-read-head instr length (3+MM+S)
#define NOUT  926
#define NTHR  512   // 2 batches/WG, 256 threads per batch-half

// Mem row stride 129: bank(129n+m)%32 = (n+m)%32 -> conflict-free both axes
#define MSTR  129

struct __align__(16) SM2 {
  float Mem[2][NN][MSTR];     // 132,096 B (persistent per-WG)
  float rw[2][RR][NN];        //   4,096 B
  float ww[2][NN];            //   1,024 B
  float instr[2][928];        //   7,424 B
  float rv[2][512];           //   4,096 B
  union {                     //   4,160 B (out_s dead by phase D)
    float out_s[2][512];
    struct { float red[2][256]; float wi[2][NN]; float invn[2][MMM]; float scal[2][8]; } d;
  } u;
};  // 152,896 B -> 1 WG/CU, 64 WGs on 256 CUs (8 per XCD; weights L2-resident)

// ---------------- per-half (256-thread) reductions; all 512 threads call together ----
__device__ __forceinline__ float red_sum_half(float v, volatile float* scal4, int tid) {
  #pragma unroll
  for (int m = 32; m >= 1; m >>= 1) v += __shfl_xor(v, m);
  if ((tid & 63) == 0) scal4[(tid >> 6) & 3] = v;
  __syncthreads();
  float r = scal4[0] + scal4[1] + scal4[2] + scal4[3];
  __syncthreads();
  return r;
}
__device__ __forceinline__ float red_max_half(float v, volatile float* scal4, int tid) {
  #pragma unroll
  for (int m = 32; m >= 1; m >>= 1) v = fmaxf(v, __shfl_xor(v, m));
  if ((tid & 63) == 0) scal4[(tid >> 6) & 3] = v;
  __syncthreads();
  float r = fmaxf(fmaxf(scal4[0], scal4[1]), fmaxf(scal4[2], scal4[3]));
  __syncthreads();
  return r;
}

// ---------------- precompute: d_out = X(8192x512) @ Wc[0:512,:] + bc ----------------
__global__ __launch_bounds__(256) void pre_mm(const float* __restrict__ X,
                                              const float* __restrict__ Wc,
                                              const float* __restrict__ bc,
                                              float* __restrict__ out) {
  __shared__ float Xs[16][68];
  __shared__ float Ws[16][64];
  const int wg = blockIdx.x;
  const int r0 = (wg >> 3) * 64, c0 = (wg & 7) * 64;
  const int tid = threadIdx.x;
  const int ti = tid >> 4, tj = tid & 15;
  float acc[4][4] = {};
  for (int kk = 0; kk < 512; kk += 16) {
    __syncthreads();
    for (int e = tid; e < 1024; e += 256) {
      int i = e >> 4, k = e & 15;
      Xs[k][i] = X[(size_t)(r0 + i) * 512 + kk + k];
    }
    for (int e = tid; e < 1024; e += 256) {
      int k = e >> 6, j = e & 63;
      Ws[k][j] = Wc[(size_t)(kk + k) * CTRL + c0 + j];
    }
    __syncthreads();
    #pragma unroll
    for (int k = 0; k < 16; ++k) {
      float a0 = Xs[k][ti*4+0], a1 = Xs[k][ti*4+1], a2 = Xs[k][ti*4+2], a3 = Xs[k][ti*4+3];
      float b0 = Ws[k][tj*4+0], b1 = Ws[k][tj*4+1], b2 = Ws[k][tj*4+2], b3 = Ws[k][tj*4+3];
      acc[0][0]+=a0*b0; acc[0][1]+=a0*b1; acc[0][2]+=a0*b2; acc[0][3]+=a0*b3;
      acc[1][0]+=a1*b0; acc[1][1]+=a1*b1; acc[1][2]+=a1*b2; acc[1][3]+=a1*b3;
      acc[2][0]+=a2*b0; acc[2][1]+=a2*b1; acc[2][2]+=a2*b2; acc[2][3]+=a2*b3;
      acc[3][0]+=a3*b0; acc[3][1]+=a3*b1; acc[3][2]+=a3*b2; acc[3][3]+=a3*b3;
    }
  }
  #pragma unroll
  for (int i = 0; i < 4; ++i) {
    size_t o = (size_t)(r0 + ti*4 + i) * 512 + c0 + tj*4;
    float4 v = { acc[i][0] + bc[c0+tj*4+0], acc[i][1] + bc[c0+tj*4+1],
                 acc[i][2] + bc[c0+tj*4+2], acc[i][3] + bc[c0+tj*4+3] };
    *(float4*)&out[o] = v;
  }
}

// ---------------- persistent per-batch-pair kernel: NO grid sync ----------------
__global__ __launch_bounds__(512) void ntm2(const float* __restrict__ Wc,
                                            const float* __restrict__ Wk,
                                            const float* __restrict__ bk,
                                            float* __restrict__ out) {
  __shared__ SM2 sm;
  const int wg = blockIdx.x, tid = threadIdx.x;
  const int b0 = wg * 2;
  const int lt = tid & 255, bb = tid >> 8;   // half-local id / batch within WG
  const int j  = tid;                        // column id for GEMV phases

  // ---- init state ----
  for (int e = tid; e < 2 * NN * MMM; e += NTHR) {
    int bl = e >> 14, n = (e >> 7) & 127;
    sm.Mem[bl][n][e & 127] = (n == NN / 2) ? 1.0f : 0.0f;
  }
  for (int e = tid; e < 2 * RR * NN; e += NTHR) ((float*)sm.rw)[e] = 0.0f;
  for (int e = tid; e < 2 * NN;      e += NTHR) ((float*)sm.ww)[e] = 0.0f;
  for (int e = tid; e < 2 * 512;     e += NTHR) ((float*)sm.rv)[e] = 0.0f;
  __syncthreads();

  for (int t = 0; t < T_; ++t) {
    // ===== phase B: out[b][t][j] = tanh(pre + rv_b @ Wc2[:,j]) =====
    // thread j owns column j for BOTH batches -> each weight load feeds 2 FMA
    {
      float a0 = 0.f, a1 = 0.f;
      const float* wp = Wc + (size_t)INX * CTRL + j;
      for (int k4 = 0; k4 < 512; k4 += 4) {
        float4 r0 = *(const float4*)&sm.rv[0][k4];
        float4 r1 = *(const float4*)&sm.rv[1][k4];
        float w0 = wp[(size_t)(k4+0)*CTRL];
        float w1 = wp[(size_t)(k4+1)*CTRL];
        float w2 = wp[(size_t)(k4+2)*CTRL];
        float w3 = wp[(size_t)(k4+3)*CTRL];
        a0 += r0.x*w0 + r0.y*w1 + r0.z*w2 + r0.w*w3;
        a1 += r1.x*w0 + r1.y*w1 + r1.z*w2 + r1.w*w3;
      }
      size_t o0 = ((size_t)(b0+0)*T_ + t)*CTRL + j;
      size_t o1 = ((size_t)(b0+1)*T_ + t)*CTRL + j;
      float v0 = tanhf(out[o0] + a0);
      float v1 = tanhf(out[o1] + a1);
      out[o0] = v0; out[o1] = v1;
      sm.u.out_s[0][j] = v0; sm.u.out_s[1][j] = v1;
    }
    __syncthreads();

    // ===== phase C: instr = out_t @ Wk + bk =====
    // thread j owns cols j and j+512 (if <926) for both batches: 2 loads -> 4 FMA
    {
      const int c1 = (j < NOUT - 512) ? j + 512 : j;   // clamp to stay in-bounds
      float a00 = 0.f, a10 = 0.f, a01 = 0.f, a11 = 0.f;
      const float* wp0 = Wk + j;
      const float* wp1 = Wk + c1;
      for (int k4 = 0; k4 < 512; k4 += 4) {
        float4 o0 = *(const float4*)&sm.u.out_s[0][k4];
        float4 o1 = *(const float4*)&sm.u.out_s[1][k4];
        #pragma unroll
        for (int i = 0; i < 4; ++i) {
          float w0 = wp0[(size_t)(k4+i)*NOUT];
          float w1 = wp1[(size_t)(k4+i)*NOUT];
          float e0 = (i==0)? o0.x : (i==1)? o0.y : (i==2)? o0.z : o0.w;
          float e1 = (i==0)? o1.x : (i==1)? o1.y : (i==2)? o1.z : o1.w;
          a00 += e0 * w0; a01 += e0 * w1;
          a10 += e1 * w0; a11 += e1 * w1;
        }
      }
      sm.instr[0][j] = a00 + bk[j];
      sm.instr[1][j] = a10 + bk[j];
      if (j < NOUT - 512) {
        sm.instr[0][j+512] = a01 + bk[j+512];
        sm.instr[1][j+512] = a11 + bk[j+512];
      }
    }
    __syncthreads();

    // ===== phase D: heads + Mem update + rv (halves: 256 threads per batch) =====
    {
      volatile float* scal4 = sm.u.d.scal[bb];
      // column inv-norms over n (reference: _l2n(Mem, axis=1))
      {
        int m = lt & 127, h = lt >> 7;
        float p = 0.f;
        #pragma unroll 8
        for (int q = 0; q < 64; ++q) { float v = sm.Mem[bb][h*64+q][m]; p += v*v; }
        sm.u.d.red[bb][lt] = p;
      }
      __syncthreads();
      if (lt < 128) sm.u.d.invn[bb][lt] =
          rsqrtf(fmaxf(sm.u.d.red[bb][lt] + sm.u.d.red[bb][lt+128], 1e-12f));
      __syncthreads();

      for (int hd = 0; hd < 5; ++hd) {
        const int off = (hd < RR) ? hd * LLh : RR * LLh;
        float kv = (lt < 128) ? sm.instr[bb][off + lt] : 0.f;
        float kn2 = red_sum_half(kv * kv, scal4, tid);
        float invk = rsqrtf(fmaxf(kn2, 1e-12f));
        float beta = expf(sm.instr[bb][off + 128]);
        float gg = 1.f / (1.f + expf(-sm.instr[bb][off + 129]));
        float s0 = sm.instr[bb][off + 130], s1 = sm.instr[bb][off + 131], s2 = sm.instr[bb][off + 132];
        float smx = fmaxf(s0, fmaxf(s1, s2));
        float e0 = expf(s0 - smx), e1 = expf(s1 - smx), e2 = expf(s2 - smx);
        float esm = e0 + e1 + e2; s0 = e0/esm; s1 = e1/esm; s2 = e2/esm;
        float spx = sm.instr[bb][off + 133];
        float tt = ((spx > 20.f) ? spx : log1pf(expf(spx))) + 1.0f;
        // sim[n] = (sum_m Mem[n][m]*invn[m]*k[m]) * invk * beta
        {
          int n = lt & 127, h = lt >> 7;
          float p = 0.f;
          #pragma unroll 8
          for (int q = 0; q < 64; ++q) {
            int m = h * 64 + q;
            p += sm.Mem[bb][n][m] * sm.u.d.invn[bb][m] * sm.instr[bb][off + m];
          }
          sm.u.d.red[bb][lt] = p;
        }
        __syncthreads();
        float simv = -1e30f, evv = 0.f;
        if (lt < 128) simv = (sm.u.d.red[bb][lt] + sm.u.d.red[bb][lt+128]) * invk * beta;
        float mx = red_max_half(simv, scal4, tid);
        if (lt < 128) evv = expf(simv - mx);
        float es = red_sum_half(evv, scal4, tid);
        if (lt < 128) {
          float wcv = evv / es;
          float wold = (hd < RR) ? sm.rw[bb][hd][lt] : sm.ww[bb][lt];
          sm.u.d.wi[bb][lt] = gg * wcv + (1.f - gg) * wold;
        }
        __syncthreads();
        float pv = 0.f;
        if (lt < 128) {
          float wsv = s0 * sm.u.d.wi[bb][(lt + 127) & 127] + s1 * sm.u.d.wi[bb][lt]
                    + s2 * sm.u.d.wi[bb][(lt + 1) & 127];
          pv = powf(wsv, tt);
        }
        float ps = red_sum_half(pv, scal4, tid);
        if (lt < 128) {
          float wn = pv / (ps + 1e-12f);
          if (hd < RR) sm.rw[bb][hd][lt] = wn; else sm.ww[bb][lt] = wn;
        }
        __syncthreads();
      }
      // Mem = Mem*(1 - ww[n]*e[m]) + ww[n]*a[m]
      for (int e = lt; e < NN * MMM; e += 256) {
        int n = e >> 7, m = e & 127;
        float w = sm.ww[bb][n];
        sm.Mem[bb][n][m] = sm.Mem[bb][n][m] * (1.f - w * sm.instr[bb][670 + m])
                         + w * sm.instr[bb][798 + m];
      }
      __syncthreads();
      // rv[r*128+m] = sum_n Mem[n][m] * rw[r][n]
      for (int e = lt; e < RR * MMM; e += 256) {
        int r = e >> 7, m = e & 127;
        float acc = 0.f;
        #pragma unroll 8
        for (int n = 0; n < NN; ++n) acc += sm.Mem[bb][n][m] * sm.rw[bb][r][n];
        sm.rv[bb][e] = acc;
      }
    }
    __syncthreads();   // rv ready for next step's phase B
  }
}

// ---------------- launch ----------------
extern "C" void kernel_launch(void* const* d_in, const int* in_sizes, int n_in,
                              void* d_out, int out_size, void* d_ws, size_t ws_size,
                              hipStream_t stream) {
  const float* x  = (const float*)d_in[0];
  const float* Wc = (const float*)d_in[1];
  const float* bc = (const float*)d_in[2];
  const float* Wk = (const float*)d_in[3];
  const float* bk = (const float*)d_in[4];
  float* out = (float*)d_out;

  pre_mm<<<dim3(1024), dim3(256), 0, stream>>>(x, Wc, bc, out);
  ntm2<<<dim3(B_ / 2), dim3(NTHR), 0, stream>>>(Wc, Wk, bk, out);
}